// Round 5
// baseline (303.332 us; speedup 1.0000x reference)
//
#include <hip/hip_runtime.h>

#define Bb 4
#define Ss 512
#define Dd 512
#define Rr 64
#define DR (Dd * Rr)            // 32768 rows of U1

#define NBLK 1024
#define NTHR 256

// ws layout in floats: [hbar 2048][cvec 256][pad][bar0 @2560][bar1 @2576][pad][Wp @4096]
#define OFF_HBAR 0
#define OFF_CVEC 2048
#define OFF_BAR  2560
#define OFF_WP   4096
#define ZERO_BYTES (4096 * 4)   // memset covers hbar, cvec, barriers

__device__ __forceinline__ void grid_barrier(unsigned* bar, unsigned target) {
    __syncthreads();            // all block's prior mem ops drained (compiler waitcnt)
    if (threadIdx.x == 0) {
        // release: writes back this XCD's dirty L2 before arrival
        __hip_atomic_fetch_add(bar, 1u, __ATOMIC_RELEASE, __HIP_MEMORY_SCOPE_AGENT);
        while (__hip_atomic_load(bar, __ATOMIC_ACQUIRE, __HIP_MEMORY_SCOPE_AGENT) < target) {
            __builtin_amdgcn_s_sleep(2);
        }
    }
    __syncthreads();
    // acquire for all threads: invalidate stale L1/L2 before reading others' data
    __builtin_amdgcn_fence(__ATOMIC_ACQUIRE, "agent");
}

__global__ __launch_bounds__(NTHR, 4) void mega(const float* __restrict__ hf,
                                                const float* __restrict__ hb,
                                                const float* __restrict__ U1,
                                                const float* __restrict__ U2,
                                                const float* __restrict__ bias,
                                                float* __restrict__ ws,
                                                float* __restrict__ out) {
    float* hbar = ws + OFF_HBAR;
    float* cvec = ws + OFF_CVEC;
    unsigned* bar = (unsigned*)(ws + OFF_BAR);
    float* Wp = ws + OFF_WP;
    __shared__ float red[4][2][64];

    const int t = threadIdx.x;
    const int g = blockIdx.x;
    const int lane = t & 63;
    const int w4 = t >> 6;                       // wave in block

    // ---------------- P1: hbar[b,j] = mean_y hb[b,y,j] (blocks 0..255) ------
    if (g < 256) {
        int b = g >> 6, ych = g & 63;
        const float* p = hb + ((size_t)(b * Ss) + ych * 8) * Dd + t;
        float s0 = 0.f, s1 = 0.f;
        #pragma unroll
        for (int y = 0; y < 8; ++y) {
            s0 += p[(size_t)y * Dd];
            s1 += p[(size_t)y * Dd + 256];
        }
        atomicAdd(&hbar[b * Dd + t],       s0 * (1.0f / Ss));
        atomicAdd(&hbar[b * Dd + t + 256], s1 * (1.0f / Ss));
    }
    grid_barrier(&bar[0], NBLK);

    // ---------------- P2: Wp[b,row] = U1[row,:]·hbar[b,:] + U2[row]; cvec ---
    {
        const int w = (g << 2) | w4;             // global wave 0..4095
        const int lm1 = lane & 1, lm2 = lane & 2;
        float4 h[Bb][2];
        #pragma unroll
        for (int b = 0; b < Bb; ++b) {
            #pragma unroll
            for (int k = 0; k < 2; ++k)
                h[b][k] = *(const float4*)(hbar + b * Dd + k * 256 + lane * 4);
        }
        #pragma unroll
        for (int pass = 0; pass < 2; ++pass) {
            int quad = 2 * w + pass;             // 4 rows per quad
            const float4* pu = (const float4*)(U1 + ((size_t)quad << 2) * Dd) + lane;
            float4 uu[8];
            #pragma unroll
            for (int q = 0; q < 4; ++q) {
                uu[2 * q]     = pu[q * 128];
                uu[2 * q + 1] = pu[q * 128 + 64];
            }
            #pragma unroll
            for (int q = 0; q < 4; ++q) {
                int row = (quad << 2) | q;
                float4 u0 = uu[2 * q], u1 = uu[2 * q + 1];
                float a[4];
                #pragma unroll
                for (int b = 0; b < Bb; ++b) {
                    a[b] = u0.x * h[b][0].x + u0.y * h[b][0].y +
                           u0.z * h[b][0].z + u0.w * h[b][0].w +
                           u1.x * h[b][1].x + u1.y * h[b][1].y +
                           u1.z * h[b][1].z + u1.w * h[b][1].w;
                }
                float snd, rcv, s01, s23, tt;
                snd = lm1 ? a[0] : a[1];
                rcv = __shfl_xor(snd, 1, 64);
                s01 = (lm1 ? a[1] : a[0]) + rcv;
                snd = lm1 ? a[2] : a[3];
                rcv = __shfl_xor(snd, 1, 64);
                s23 = (lm1 ? a[3] : a[2]) + rcv;
                snd = lm2 ? s01 : s23;
                rcv = __shfl_xor(snd, 2, 64);
                tt  = (lm2 ? s23 : s01) + rcv;
                tt += __shfl_xor(tt, 4, 64);
                tt += __shfl_xor(tt, 8, 64);
                tt += __shfl_xor(tt, 16, 64);
                tt += __shfl_xor(tt, 32, 64);
                if (lane < 4)
                    Wp[(size_t)lane * DR + row] = tt + U2[row];
            }
        }
        // cvec jobs on 16 spread waves: cvec[b,r] = bias[r] + hbar[b]·U2[D:]
        if ((w & 255) == 255) {
            int c = w >> 8;                      // 0..15
            int b = c >> 2, jc = c & 3;
            const float* hsrc = hbar + b * Dd + jc * 128;
            const float* u = U2 + (size_t)(Dd + jc * 128) * Rr + lane;
            float acc = (jc == 0) ? bias[lane] : 0.f;
            #pragma unroll 8
            for (int j = 0; j < 128; ++j)
                acc = fmaf(hsrc[j], u[(size_t)j * Rr], acc);
            atomicAdd(&cvec[(b << 6) + lane], acc);
        }
    }
    grid_barrier(&bar[1], NBLK);

    // ---------------- P3: out[b,x,r] = hf[b,x,:]·Wp[b,:,r] + cvec[b,r] ------
    {
        int b  = g >> 8;
        int xp = g & 255;
        int x0 = xp * 2;
        int i0 = w4 * 128;                       // wave's i-quarter
        const float* wp = Wp + (size_t)b * DR + (size_t)i0 * Rr + lane;
        const float* hp = hf + ((size_t)(b * Ss) + x0) * Dd + i0;
        float a0 = 0.f, a1 = 0.f;
        #pragma unroll 4
        for (int c = 0; c < 32; ++c) {
            float wA = wp[(size_t)(4 * c + 0) * Rr];
            float wB = wp[(size_t)(4 * c + 1) * Rr];
            float wC = wp[(size_t)(4 * c + 2) * Rr];
            float wD = wp[(size_t)(4 * c + 3) * Rr];
            float4 h0 = *(const float4*)(hp + 4 * c);
            float4 h1 = *(const float4*)(hp + Dd + 4 * c);
            a0 = fmaf(h0.x, wA, a0); a0 = fmaf(h0.y, wB, a0);
            a0 = fmaf(h0.z, wC, a0); a0 = fmaf(h0.w, wD, a0);
            a1 = fmaf(h1.x, wA, a1); a1 = fmaf(h1.y, wB, a1);
            a1 = fmaf(h1.z, wC, a1); a1 = fmaf(h1.w, wD, a1);
        }
        red[w4][0][lane] = a0;
        red[w4][1][lane] = a1;
        __syncthreads();
        if (t < 128) {
            int xk = t >> 6, rr = t & 63;
            float v = red[0][xk][rr] + red[1][xk][rr] +
                      red[2][xk][rr] + red[3][xk][rr] + cvec[(b << 6) + rr];
            out[((size_t)(b * Ss) + x0 + xk) * Rr + rr] = v;
        }
    }
}

extern "C" void kernel_launch(void* const* d_in, const int* in_sizes, int n_in,
                              void* d_out, int out_size, void* d_ws, size_t ws_size,
                              hipStream_t stream) {
    const float* hf   = (const float*)d_in[0];   // [B,S,D]
    const float* hb   = (const float*)d_in[1];   // [B,S,D]
    const float* U1   = (const float*)d_in[2];   // [D,R,D]
    const float* U2   = (const float*)d_in[3];   // [2D,R]
    const float* bias = (const float*)d_in[4];   // [R]
    float* out = (float*)d_out;                  // [B,S,R]
    float* ws  = (float*)d_ws;

    (void)hipMemsetAsync(d_ws, 0, ZERO_BYTES, stream); // zero hbar, cvec, barriers
    mega<<<NBLK, NTHR, 0, stream>>>(hf, hb, U1, U2, bias, ws, out);
}

// Round 6
// 47.331 us; speedup vs baseline: 6.4087x; 6.4087x over previous
//
#include <hip/hip_runtime.h>

#define Bb 4
#define Ss 512
#define Dd 512
#define Rr 64
#define DR (Dd * Rr)            // 32768 rows of U1
#define NCH 32                  // y-chunks for partial mean
#define YPER (Ss / NCH)         // 16

// ---------------- K1: partial sums over y for h_backward mean ----------------
__global__ __launch_bounds__(512) void k1_partial(const float* __restrict__ hb,
                                                  float* __restrict__ part) {
    int b  = blockIdx.x >> 5;          // /NCH
    int ch = blockIdx.x & 31;
    int j  = threadIdx.x;              // 0..511
    const float* p = hb + ((size_t)(b * Ss) + ch * YPER) * Dd + j;
    float acc = 0.f;
    #pragma unroll
    for (int y = 0; y < YPER; ++y) acc += p[(size_t)y * Dd];
    part[(size_t)blockIdx.x * Dd + j] = acc;   // part[(b*NCH+ch)*D + j]
}

// ---------------- K2a: finalize hbar = mean_y hb ----------------
__global__ __launch_bounds__(256) void k2a_hbar(const float* __restrict__ part,
                                                float* __restrict__ hbar) {
    int idx = blockIdx.x * 256 + threadIdx.x;  // 0..2047  (b*512 + j)
    const float* p = part + ((size_t)(idx >> 9) * NCH) * Dd + (idx & 511);
    float acc = 0.f;
    #pragma unroll
    for (int ch = 0; ch < NCH; ++ch) acc += p[(size_t)ch * Dd];
    hbar[idx] = acc * (1.0f / Ss);
}

// ---------------- K2w: lane-owns-row formulation (NO cross-lane reduce) ------
// blocks 0..511: block = i (0..511). Lane r owns row i*64+r for all 4 batches.
// Wave w4 covers j in [w4*128, w4*128+128); 4-way LDS reduce; coalesced store.
// blocks 512..515: cvec[b,r] = bias[r] + sum_j hbar[b,j]*U2[D+j,r]
__global__ __launch_bounds__(256) void k2w(const float* __restrict__ U1,
                                           const float* __restrict__ U2,
                                           const float* __restrict__ bias,
                                           const float* __restrict__ hbar,
                                           float* __restrict__ Wp,
                                           float* __restrict__ cvec) {
    __shared__ float red[4][4][64];     // [wave][batch][lane]
    const int t = threadIdx.x;
    const int lane = t & 63;
    const int w4 = t >> 6;
    const int g = blockIdx.x;

    if (g >= 512) {                     // cvec jobs
        int b = g - 512;
        const float* hsrc = hbar + b * Dd + w4 * 128;
        const float* u = U2 + (size_t)(Dd + w4 * 128) * Rr + lane;
        float acc = (w4 == 0) ? bias[lane] : 0.f;
        #pragma unroll 8
        for (int j = 0; j < 128; ++j)
            acc = fmaf(hsrc[j], u[(size_t)j * Rr], acc);
        red[w4][0][lane] = acc;
        __syncthreads();
        if (t < 64)
            cvec[(b << 6) + t] = red[0][0][t] + red[1][0][t] +
                                 red[2][0][t] + red[3][0][t];
        return;
    }

    const int i = g;                    // 0..511
    // lane's U1 row slice: row = i*64+lane, j in [w4*128, +128)
    const float* pu  = U1 + ((size_t)(i * 64 + lane)) * Dd + w4 * 128;
    const float* hb0 = hbar + w4 * 128;
    float a0 = 0.f, a1 = 0.f, a2 = 0.f, a3 = 0.f;
    #pragma unroll 8
    for (int j = 0; j < 128; j += 4) {
        float4 u  = *(const float4*)(pu + j);
        float4 h0 = *(const float4*)(hb0 + 0 * Dd + j);   // uniform (scalar) loads
        float4 h1 = *(const float4*)(hb0 + 1 * Dd + j);
        float4 h2 = *(const float4*)(hb0 + 2 * Dd + j);
        float4 h3 = *(const float4*)(hb0 + 3 * Dd + j);
        a0 = fmaf(u.x, h0.x, a0); a0 = fmaf(u.y, h0.y, a0);
        a0 = fmaf(u.z, h0.z, a0); a0 = fmaf(u.w, h0.w, a0);
        a1 = fmaf(u.x, h1.x, a1); a1 = fmaf(u.y, h1.y, a1);
        a1 = fmaf(u.z, h1.z, a1); a1 = fmaf(u.w, h1.w, a1);
        a2 = fmaf(u.x, h2.x, a2); a2 = fmaf(u.y, h2.y, a2);
        a2 = fmaf(u.z, h2.z, a2); a2 = fmaf(u.w, h2.w, a2);
        a3 = fmaf(u.x, h3.x, a3); a3 = fmaf(u.y, h3.y, a3);
        a3 = fmaf(u.z, h3.z, a3); a3 = fmaf(u.w, h3.w, a3);
    }
    red[w4][0][lane] = a0;
    red[w4][1][lane] = a1;
    red[w4][2][lane] = a2;
    red[w4][3][lane] = a3;
    __syncthreads();
    // thread t: batch = w4, output row = i*64 + lane; coalesced 256B stores
    {
        float v = red[0][w4][lane] + red[1][w4][lane] +
                  red[2][w4][lane] + red[3][w4][lane] + U2[i * 64 + lane];
        Wp[(size_t)w4 * DR + i * 64 + lane] = v;
    }
}

// ---------------- K3: out[b,x,r] = hf[b,x,:]·Wp[b,:,r] + cvec[b,r] -----------
// grid 1024: (b, x-pair); block 256 = 4 waves; wave = i-quarter; LDS reduce.
__global__ __launch_bounds__(256) void k3(const float* __restrict__ hf,
                                          const float* __restrict__ Wp,
                                          const float* __restrict__ cvec,
                                          float* __restrict__ out) {
    __shared__ float red[4][2][64];
    const int t = threadIdx.x;
    const int lane = t & 63;
    const int w4 = t >> 6;
    int b  = blockIdx.x >> 8;
    int xp = blockIdx.x & 255;
    int x0 = xp * 2;
    int i0 = w4 * 128;
    const float* wp = Wp + (size_t)b * DR + (size_t)i0 * Rr + lane;
    const float* hp = hf + ((size_t)(b * Ss) + x0) * Dd + i0;
    float a0 = 0.f, a1 = 0.f;
    #pragma unroll 4
    for (int c = 0; c < 32; ++c) {
        float wA = wp[(size_t)(4 * c + 0) * Rr];
        float wB = wp[(size_t)(4 * c + 1) * Rr];
        float wC = wp[(size_t)(4 * c + 2) * Rr];
        float wD = wp[(size_t)(4 * c + 3) * Rr];
        float4 h0 = *(const float4*)(hp + 4 * c);
        float4 h1 = *(const float4*)(hp + Dd + 4 * c);
        a0 = fmaf(h0.x, wA, a0); a0 = fmaf(h0.y, wB, a0);
        a0 = fmaf(h0.z, wC, a0); a0 = fmaf(h0.w, wD, a0);
        a1 = fmaf(h1.x, wA, a1); a1 = fmaf(h1.y, wB, a1);
        a1 = fmaf(h1.z, wC, a1); a1 = fmaf(h1.w, wD, a1);
    }
    red[w4][0][lane] = a0;
    red[w4][1][lane] = a1;
    __syncthreads();
    if (t < 128) {
        int xk = t >> 6, rr = t & 63;
        float v = red[0][xk][rr] + red[1][xk][rr] +
                  red[2][xk][rr] + red[3][xk][rr] + cvec[(b << 6) + rr];
        out[((size_t)(b * Ss) + x0 + xk) * Rr + rr] = v;
    }
}

extern "C" void kernel_launch(void* const* d_in, const int* in_sizes, int n_in,
                              void* d_out, int out_size, void* d_ws, size_t ws_size,
                              hipStream_t stream) {
    const float* hf   = (const float*)d_in[0];   // [B,S,D]
    const float* hb   = (const float*)d_in[1];   // [B,S,D]
    const float* U1   = (const float*)d_in[2];   // [D,R,D]
    const float* U2   = (const float*)d_in[3];   // [2D,R]
    const float* bias = (const float*)d_in[4];   // [R]
    float* out = (float*)d_out;                  // [B,S,R]

    float* ws   = (float*)d_ws;
    float* part = ws;                            // B*NCH*D = 65536
    float* hbar = part + (size_t)Bb * NCH * Dd;  // B*D     = 2048
    float* cvec = hbar + (size_t)Bb * Dd;        // B*R     = 256
    float* Wp   = cvec + (size_t)Bb * Rr;        // B*D*R   = 131072

    k1_partial<<<Bb * NCH, 512, 0, stream>>>(hb, part);
    k2a_hbar<<<(Bb * Dd) / 256, 256, 0, stream>>>(part, hbar);
    k2w<<<516, 256, 0, stream>>>(U1, U2, bias, hbar, Wp, cvec);
    k3<<<1024, 256, 0, stream>>>(hf, Wp, cvec, out);
}

// Round 7
// 39.160 us; speedup vs baseline: 7.7460x; 1.2087x over previous
//
#include <hip/hip_runtime.h>

#define Bb 4
#define Ss 512
#define Dd 512
#define Rr 64
#define DR (Dd * Rr)            // 32768 rows of U1
#define NYC 16                  // y-chunks for partial mean
#define YPC (Ss / NYC)          // 32

// ---------------- kA: part[(b*NYC+yc)*D + j] = (1/S)*sum_{y in chunk} hb ----
// 64 blocks; disjoint overwrite (no init / atomics needed -> replay-safe).
__global__ __launch_bounds__(256) void kA(const float* __restrict__ hb,
                                          float* __restrict__ part) {
    int g = blockIdx.x;                 // 0..63
    int b = g >> 4, yc = g & 15;
    const float* p = hb + ((size_t)(b * Ss) + yc * YPC) * Dd;
    int j0 = threadIdx.x, j1 = threadIdx.x + 256;
    float s0 = 0.f, s1 = 0.f;
    #pragma unroll 8
    for (int y = 0; y < YPC; ++y) {
        s0 += p[(size_t)y * Dd + j0];
        s1 += p[(size_t)y * Dd + j1];
    }
    part[(size_t)g * Dd + j0] = s0 * (1.0f / Ss);
    part[(size_t)g * Dd + j1] = s1 * (1.0f / Ss);
}

// ---------------- kB: Wp + cvec, with in-block hbar reduction ----------------
// Every block first reduces part[64][512] -> hbar LDS (128KB L2/L3 reads).
// blocks 0..511: block i covers U1 rows [i*64, i*64+64); wave w4 -> 4 quads.
//   Quad path = R3's proven coalesced float4 + pair-merge/butterfly reduce.
// blocks 512..515: cvec[b,r] = bias[r] + sum_j hbar[b,j]*U2[D+j,r]
__global__ __launch_bounds__(256) void kB(const float* __restrict__ U1,
                                          const float* __restrict__ U2,
                                          const float* __restrict__ bias,
                                          const float* __restrict__ part,
                                          float* __restrict__ Wp,
                                          float* __restrict__ cvec) {
    __shared__ float hsh[Bb][Dd];       // 8KB
    __shared__ float red[4][64];        // 1KB (cvec blocks only)
    const int t = threadIdx.x;
    const int lane = t & 63;
    const int w4 = t >> 6;
    const int g = blockIdx.x;

    // phase 1: hbar into LDS
    #pragma unroll
    for (int b = 0; b < Bb; ++b) {
        #pragma unroll
        for (int e = 0; e < 2; ++e) {
            int j = t + e * 256;
            float s = 0.f;
            #pragma unroll
            for (int yc = 0; yc < NYC; ++yc)
                s += part[(size_t)(b * NYC + yc) * Dd + j];
            hsh[b][j] = s;
        }
    }
    __syncthreads();

    if (g >= 512) {                     // cvec jobs
        int b = g - 512;
        const float* u = U2 + (size_t)(Dd + w4 * 128) * Rr + lane;
        const float* h = &hsh[b][w4 * 128];
        float acc = (w4 == 0) ? bias[lane] : 0.f;
        #pragma unroll 8
        for (int j = 0; j < 128; ++j)
            acc = fmaf(h[j], u[(size_t)j * Rr], acc);
        red[w4][lane] = acc;
        __syncthreads();
        if (t < 64)
            cvec[((b) << 6) + t] = red[0][t] + red[1][t] + red[2][t] + red[3][t];
        return;
    }

    // phase 2: lane's hbar fragments -> registers (2-way LDS reads, free)
    const int lm1 = lane & 1, lm2 = lane & 2;
    float4 h[Bb][2];
    #pragma unroll
    for (int b = 0; b < Bb; ++b) {
        #pragma unroll
        for (int k = 0; k < 2; ++k)
            h[b][k] = *(const float4*)(&hsh[b][k * 256 + lane * 4]);
    }
    #pragma unroll
    for (int q4 = 0; q4 < 4; ++q4) {
        int quad = (g << 4) | (w4 << 2) | q4;            // 0..8191
        const float4* pu = (const float4*)(U1 + ((size_t)quad << 2) * Dd) + lane;
        float4 uu[8];
        #pragma unroll
        for (int q = 0; q < 4; ++q) {
            uu[2 * q]     = pu[q * 128];
            uu[2 * q + 1] = pu[q * 128 + 64];
        }
        #pragma unroll
        for (int q = 0; q < 4; ++q) {
            int row = (quad << 2) | q;                   // 0..32767
            float4 u0 = uu[2 * q], u1 = uu[2 * q + 1];
            float a[4];
            #pragma unroll
            for (int b = 0; b < Bb; ++b) {
                a[b] = u0.x * h[b][0].x + u0.y * h[b][0].y +
                       u0.z * h[b][0].z + u0.w * h[b][0].w +
                       u1.x * h[b][1].x + u1.y * h[b][1].y +
                       u1.z * h[b][1].z + u1.w * h[b][1].w;
            }
            float snd, rcv, s01, s23, tt;
            snd = lm1 ? a[0] : a[1];
            rcv = __shfl_xor(snd, 1, 64);
            s01 = (lm1 ? a[1] : a[0]) + rcv;
            snd = lm1 ? a[2] : a[3];
            rcv = __shfl_xor(snd, 1, 64);
            s23 = (lm1 ? a[3] : a[2]) + rcv;
            snd = lm2 ? s01 : s23;
            rcv = __shfl_xor(snd, 2, 64);
            tt  = (lm2 ? s23 : s01) + rcv;
            tt += __shfl_xor(tt, 4, 64);
            tt += __shfl_xor(tt, 8, 64);
            tt += __shfl_xor(tt, 16, 64);
            tt += __shfl_xor(tt, 32, 64);
            if (lane < 4)
                Wp[(size_t)lane * DR + row] = tt + U2[row];
        }
    }
}

// ---------------- kC: out[b,x,r] = hf[b,x,:]·Wp[b,:,r] + cvec[b,r] -----------
// grid 1024: (b, x-pair); block 256 = 4 waves; wave = i-quarter; LDS reduce.
__global__ __launch_bounds__(256) void kC(const float* __restrict__ hf,
                                          const float* __restrict__ Wp,
                                          const float* __restrict__ cvec,
                                          float* __restrict__ out) {
    __shared__ float red[4][2][64];
    const int t = threadIdx.x;
    const int lane = t & 63;
    const int w4 = t >> 6;
    int b  = blockIdx.x >> 8;
    int xp = blockIdx.x & 255;
    int x0 = xp * 2;
    int i0 = w4 * 128;
    const float* wp = Wp + (size_t)b * DR + (size_t)i0 * Rr + lane;
    const float* hp = hf + ((size_t)(b * Ss) + x0) * Dd + i0;
    float a0 = 0.f, a1 = 0.f;
    #pragma unroll 4
    for (int c = 0; c < 32; ++c) {
        float wA = wp[(size_t)(4 * c + 0) * Rr];
        float wB = wp[(size_t)(4 * c + 1) * Rr];
        float wC = wp[(size_t)(4 * c + 2) * Rr];
        float wD = wp[(size_t)(4 * c + 3) * Rr];
        float4 h0 = *(const float4*)(hp + 4 * c);
        float4 h1 = *(const float4*)(hp + Dd + 4 * c);
        a0 = fmaf(h0.x, wA, a0); a0 = fmaf(h0.y, wB, a0);
        a0 = fmaf(h0.z, wC, a0); a0 = fmaf(h0.w, wD, a0);
        a1 = fmaf(h1.x, wA, a1); a1 = fmaf(h1.y, wB, a1);
        a1 = fmaf(h1.z, wC, a1); a1 = fmaf(h1.w, wD, a1);
    }
    red[w4][0][lane] = a0;
    red[w4][1][lane] = a1;
    __syncthreads();
    if (t < 128) {
        int xk = t >> 6, rr = t & 63;
        float v = red[0][xk][rr] + red[1][xk][rr] +
                  red[2][xk][rr] + red[3][xk][rr] + cvec[(b << 6) + rr];
        out[((size_t)(b * Ss) + x0 + xk) * Rr + rr] = v;
    }
}

extern "C" void kernel_launch(void* const* d_in, const int* in_sizes, int n_in,
                              void* d_out, int out_size, void* d_ws, size_t ws_size,
                              hipStream_t stream) {
    const float* hf   = (const float*)d_in[0];   // [B,S,D]
    const float* hb   = (const float*)d_in[1];   // [B,S,D]
    const float* U1   = (const float*)d_in[2];   // [D,R,D]
    const float* U2   = (const float*)d_in[3];   // [2D,R]
    const float* bias = (const float*)d_in[4];   // [R]
    float* out = (float*)d_out;                  // [B,S,R]

    float* ws   = (float*)d_ws;
    float* part = ws;                            // 64*512 = 32768 floats
    float* cvec = part + (size_t)64 * Dd;        // 256
    float* Wp   = cvec + (size_t)Bb * Rr;        // B*D*R = 131072

    kA<<<64, 256, 0, stream>>>(hb, part);
    kB<<<516, 256, 0, stream>>>(U1, U2, bias, part, Wp, cvec);
    kC<<<1024, 256, 0, stream>>>(hf, Wp, cvec, out);
}